// Round 2
// baseline (158.710 us; speedup 1.0000x reference)
//
#include <hip/hip_runtime.h>
#include <cfloat>

#define TPB 256
#define BKT 32768                 // buckets per side (2048 per unit over [-8,8))
#define SLOTS 16                  // floats per bucket = one 64B line
#define OVCAP 4096                // overflow capacity per side (expected ~0 used)
#define RLO -8.0f
#define RSCALE (BKT / 16.0f)      // exact power of two
#define ALPHA 0.5f

// ---- workspace layout (uint words) -------------------------------------
// zeroed region (one hipMemsetAsync):
#define CNT_OFF   0                       // cnt[2*BKT]
#define PMAX_OFF  (2 * BKT)               // max enc per bucket
#define CMAX_OFF  (4 * BKT)               // max ~enc per bucket (== min elem)
#define BM1_OFF   (6 * BKT)               // occupancy bits: 2*1024 words
#define BM2_OFF   (6 * BKT + 2048)        // level-2 bits:    2*32 words
#define OVC_OFF   (6 * BKT + 2048 + 64)   // overflow counters: 2 words
#define ZERO_WORDS (6 * BKT + 2048 + 64 + 2)
// not zeroed:
#define SLOTS_OFF (((ZERO_WORDS) + 63) & ~63)          // float slots, 2*BKT*SLOTS
#define OVF_OFF   (SLOTS_OFF + 2 * BKT * SLOTS)        // float overflow, 2*OVCAP

// Order-preserving float <-> uint transform (monotone on finite floats;
// enc/~enc of any finite float is nonzero, so 0 == empty sentinel).
__device__ __forceinline__ unsigned enc_f(float v) {
    unsigned u = __float_as_uint(v);
    return (u & 0x80000000u) ? ~u : (u | 0x80000000u);
}
__device__ __forceinline__ float dec_f(unsigned e) {
    unsigned u = (e & 0x80000000u) ? (e & 0x7FFFFFFFu) : ~e;
    return __uint_as_float(u);
}
// Monotone non-decreasing (fl(v+8) monotone, *2048 exact pow2, trunc+clamp
// monotone) => bucket(u) < bucket(w) implies u < w.
__device__ __forceinline__ int bucket_of(float v) {
    int b = (int)((v - RLO) * RSCALE);
    return min(max(b, 0), BKT - 1);
}

// ---- build: histogram + per-bucket max/min + occupancy bitmap + scatter ----
// All scan-free: slot position comes from the same atomicAdd as the count.
__global__ __launch_bounds__(TPB) void
chamfer_build(const float* __restrict__ x, const float* __restrict__ y,
              int n, int m, unsigned* __restrict__ ws) {
    const int i = blockIdx.x * TPB + threadIdx.x;
    if (i >= n + m) return;
    const bool isx = i < n;
    const int side = isx ? 0 : 1;
    const float v = isx ? x[i] : y[i - n];
    const int b = bucket_of(v);
    const unsigned e = enc_f(v);

    const unsigned pos = atomicAdd(ws + CNT_OFF + side * BKT + b, 1u);
    float* slots = (float*)(ws + SLOTS_OFF);
    if (pos < SLOTS) {
        slots[((size_t)(side * BKT + b)) * SLOTS + pos] = v;
    } else {
        const unsigned o = atomicAdd(ws + OVC_OFF + side, 1u);
        if (o < OVCAP) ((float*)(ws + OVF_OFF))[side * OVCAP + o] = v;
    }
    atomicMax(ws + PMAX_OFF + side * BKT + b, e);
    atomicMax(ws + CMAX_OFF + side * BKT + b, ~e);
    atomicOr(ws + BM1_OFF + side * 1024 + (b >> 5), 1u << (b & 31));
    atomicOr(ws + BM2_OFF + side * 32 + (b >> 10), 1u << ((b >> 5) & 31));
}

// Previous/next nonempty bucket via 2-level bitmap (no walking).
__device__ __forceinline__ int prev_ne(const unsigned* __restrict__ bm1,
                                       const unsigned* __restrict__ bm2, int b) {
    if (b == 0) return -1;
    const int p = b - 1;
    unsigned w = bm1[p >> 5] & (~0u >> (31 - (p & 31)));
    if (w) return (p & ~31) | (31 - __clz(w));
    const int W = (p >> 5) - 1;
    if (W < 0) return -1;
    int j = W >> 5;
    unsigned w2 = bm2[j] & (~0u >> (31 - (W & 31)));
    while (!w2 && --j >= 0) w2 = bm2[j];
    if (!w2) return -1;
    const int Wp = (j << 5) | (31 - __clz(w2));
    return (Wp << 5) | (31 - __clz(bm1[Wp]));
}
__device__ __forceinline__ int next_ne(const unsigned* __restrict__ bm1,
                                       const unsigned* __restrict__ bm2, int b) {
    if (b >= BKT - 1) return -1;
    const int p = b + 1;
    unsigned w = bm1[p >> 5] & (~0u << (p & 31));
    if (w) return (p & ~31) | (__ffs(w) - 1);
    const int W = (p >> 5) + 1;
    if (W > 1023) return -1;
    int j = W >> 5;
    unsigned w2 = bm2[j] & (~0u << (W & 31));
    while (!w2 && ++j < 32) w2 = bm2[j];
    if (!w2) return -1;
    const int Wp = (j << 5) | (__ffs(w2) - 1);
    return (Wp << 5) | (__ffs(bm1[Wp]) - 1);
}

// ---- query: candidates = own bucket slots + max-of-prev-nonempty +
// min-of-next-nonempty + overflow list. Exact: the value-order predecessor
// and successor of v are always in this set (bucket map monotone; f32
// |v-y| rounding monotone in true distance), and every candidate is a real
// element, so min == global min. Deterministic double reduction as before.
__global__ __launch_bounds__(TPB) void
chamfer_query(const float* __restrict__ x, const float* __restrict__ y,
              int n, int m, const unsigned* __restrict__ ws,
              double* __restrict__ bsums) {
    const int q = blockIdx.x * TPB + threadIdx.x;
    const int total = n + m;
    double sx = 0.0, sy = 0.0;
    if (q < total) {
        const bool isx = q < n;
        const float v = isx ? x[q] : y[q - n];
        const int side = isx ? 1 : 0;            // search the OTHER side
        const unsigned* cnt  = ws + CNT_OFF + side * BKT;
        const unsigned* pmax = ws + PMAX_OFF + side * BKT;
        const unsigned* cmax = ws + CMAX_OFF + side * BKT;
        const unsigned* bm1  = ws + BM1_OFF + side * 1024;
        const unsigned* bm2  = ws + BM2_OFF + side * 32;
        const float* slots = (const float*)(ws + SLOTS_OFF);
        const int b = bucket_of(v);

        float best = FLT_MAX;
        const unsigned c = min(cnt[b], (unsigned)SLOTS);
        const float* sl = slots + ((size_t)(side * BKT + b)) * SLOTS;
        for (unsigned j = 0; j < c; ++j)
            best = fminf(best, fabsf(v - sl[j]));

        const int bp = prev_ne(bm1, bm2, b);
        if (bp >= 0) best = fminf(best, fabsf(v - dec_f(pmax[bp])));
        const int bn = next_ne(bm1, bm2, b);
        if (bn >= 0) best = fminf(best, fabsf(v - dec_f(~cmax[bn])));

        const unsigned oc = min(ws[OVC_OFF + side], (unsigned)OVCAP);
        const float* ovf = (const float*)(ws + OVF_OFF) + side * OVCAP;
        for (unsigned k = 0; k < oc; ++k)
            best = fminf(best, fabsf(v - ovf[k]));

        if (isx) sx = (double)best; else sy = (double)best;
    }
    for (int off = 32; off > 0; off >>= 1) {
        sx += __shfl_down(sx, off);
        sy += __shfl_down(sy, off);
    }
    __shared__ double wsx[TPB / 64], wsy[TPB / 64];
    const int w = threadIdx.x >> 6;
    if ((threadIdx.x & 63) == 0) { wsx[w] = sx; wsy[w] = sy; }
    __syncthreads();
    if (threadIdx.x == 0) {
        double tx = 0.0, ty = 0.0;
#pragma unroll
        for (int i = 0; i < TPB / 64; ++i) { tx += wsx[i]; ty += wsy[i]; }
        bsums[2 * blockIdx.x] = tx;
        bsums[2 * blockIdx.x + 1] = ty;
    }
}

__global__ __launch_bounds__(TPB) void
chamfer_final(const double* __restrict__ bsums, int nb,
              int n, int m, float* __restrict__ out) {
    double sx = 0.0, sy = 0.0;
    for (int i = threadIdx.x; i < nb; i += blockDim.x) {
        sx += bsums[2 * i];
        sy += bsums[2 * i + 1];
    }
    for (int off = 32; off > 0; off >>= 1) {
        sx += __shfl_down(sx, off);
        sy += __shfl_down(sy, off);
    }
    __shared__ double lsx[4], lsy[4];
    const int wave = threadIdx.x >> 6;
    if ((threadIdx.x & 63) == 0) { lsx[wave] = sx; lsy[wave] = sy; }
    __syncthreads();
    if (threadIdx.x == 0) {
        double tx = 0.0, ty = 0.0;
        for (int w = 0; w < (int)(blockDim.x >> 6); ++w) { tx += lsx[w]; ty += lsy[w]; }
        const double a = (double)ALPHA;
        out[0] = (float)(a * tx / (double)n + (1.0 - a) * ty / (double)m);
    }
}

extern "C" void kernel_launch(void* const* d_in, const int* in_sizes, int n_in,
                              void* d_out, int out_size, void* d_ws, size_t ws_size,
                              hipStream_t stream) {
    const float* x = (const float*)d_in[0];
    const float* y = (const float*)d_in[1];
    const int n = in_sizes[0];
    const int m = in_sizes[1];
    float* out = (float*)d_out;
    const int total = n + m;

    unsigned* ws = (unsigned*)d_ws;
    const size_t meta_bytes = (size_t)(OVF_OFF + 2 * OVCAP) * sizeof(unsigned);
    const size_t meta_al = (meta_bytes + 255) & ~(size_t)255;
    double* bsums = (double*)((char*)d_ws + meta_al);

    const int nb = (total + TPB - 1) / TPB;   // 128 blocks

    hipMemsetAsync(ws, 0, (size_t)ZERO_WORDS * sizeof(unsigned), stream);
    chamfer_build<<<nb, TPB, 0, stream>>>(x, y, n, m, ws);
    chamfer_query<<<nb, TPB, 0, stream>>>(x, y, n, m, ws, bsums);
    chamfer_final<<<nb ? 1 : 1, TPB, 0, stream>>>(bsums, nb, n, m, out);
}

// Round 3
// 78.621 us; speedup vs baseline: 2.0187x; 2.0187x over previous
//
#include <hip/hip_runtime.h>
#include <cfloat>

#define TPB 256
#define BMT 1024
#define BKT 32768                 // buckets per side (2048 per unit over [-8,8))
#define SLOTS 16                  // floats per bucket = one 64B line
#define OVCAP 4096                // overflow capacity per side (expected 0 used)
#define RLO -8.0f
#define RSCALE (BKT / 16.0f)      // exact power of two
#define ALPHA 0.5f

// ---- workspace layout (uint words) -------------------------------------
// zeroed region (one hipMemsetAsync): cnt + overflow counters ONLY.
#define CNT_OFF   0                         // cnt[2*BKT]
#define OVC_OFF   (2 * BKT)                 // 2 words
#define ZERO_WORDS (2 * BKT + 2)
// written fully by chamfer_bitmap (no zeroing needed):
#define BM1_OFF   ((ZERO_WORDS + 63) & ~63) // 2*1024 words
#define BM2_OFF   (BM1_OFF + 2048)          // 2*32 words
// written by build (reads gated by cnt):
#define SLOTS_OFF (BM2_OFF + 64)            // floats, 2*BKT*SLOTS (64B-aligned)
#define OVF_OFF   (SLOTS_OFF + 2 * BKT * SLOTS)

// Monotone non-decreasing (fl(v+8) monotone, *2048 exact pow2, trunc+clamp
// monotone) => bucket(u) < bucket(w) implies u < w.
__device__ __forceinline__ int bucket_of(float v) {
    int b = (int)((v - RLO) * RSCALE);
    return min(max(b, 0), BKT - 1);
}

// ---- build: histogram + slot scatter. ONE low-contention atomic per
// element (max ~4 hits/bucket); slot position reuses the same atomicAdd.
// No bitmap / minmax atomics here (R2 lesson: bm2 atomicOr had ~3100
// serialized ops on the central word = 90+ us).
__global__ __launch_bounds__(TPB) void
chamfer_build(const float* __restrict__ x, const float* __restrict__ y,
              int n, int m, unsigned* __restrict__ ws) {
    const int i = blockIdx.x * TPB + threadIdx.x;
    if (i >= n + m) return;
    const bool isx = i < n;
    const int side = isx ? 0 : 1;
    const float v = isx ? x[i] : y[i - n];
    const int b = bucket_of(v);
    const unsigned pos = atomicAdd(ws + CNT_OFF + side * BKT + b, 1u);
    if (pos < SLOTS) {
        ((float*)(ws + SLOTS_OFF))[((size_t)(side * BKT + b)) * SLOTS + pos] = v;
    } else {
        const unsigned o = atomicAdd(ws + OVC_OFF + side, 1u);
        if (o < OVCAP) ((float*)(ws + OVF_OFF))[side * OVCAP + o] = v;
    }
}

// ---- bitmap: derive 2-level occupancy from cnt. Single WG, zero atomics.
// bm1 word w <- 32 cnt words (8x uint4); bm2 word t <- 32 bm1 words (LDS).
__global__ __launch_bounds__(BMT) void chamfer_bitmap(unsigned* __restrict__ ws) {
    __shared__ unsigned s_bm1[2048];
    const int t = threadIdx.x;
    const uint4* cnt4 = (const uint4*)(ws + CNT_OFF);
#pragma unroll
    for (int k = 0; k < 2; ++k) {
        const int w = t + k * BMT;
        unsigned bits = 0;
#pragma unroll
        for (int j = 0; j < 8; ++j) {
            const uint4 c = cnt4[w * 8 + j];
            if (c.x) bits |= 1u << (4 * j + 0);
            if (c.y) bits |= 1u << (4 * j + 1);
            if (c.z) bits |= 1u << (4 * j + 2);
            if (c.w) bits |= 1u << (4 * j + 3);
        }
        ws[BM1_OFF + w] = bits;
        s_bm1[w] = bits;
    }
    __syncthreads();
    if (t < 64) {
        unsigned bits = 0;
#pragma unroll
        for (int j = 0; j < 32; ++j)
            if (s_bm1[t * 32 + j]) bits |= 1u << j;
        ws[BM2_OFF + t] = bits;
    }
}

// Previous/next nonempty bucket via 2-level bitmap (bounded, no bucket walk).
__device__ __forceinline__ int prev_ne(const unsigned* __restrict__ bm1,
                                       const unsigned* __restrict__ bm2, int b) {
    if (b == 0) return -1;
    const int p = b - 1;
    unsigned w = bm1[p >> 5] & (~0u >> (31 - (p & 31)));
    if (w) return (p & ~31) | (31 - __clz(w));
    const int W = (p >> 5) - 1;
    if (W < 0) return -1;
    int j = W >> 5;
    unsigned w2 = bm2[j] & (~0u >> (31 - (W & 31)));
    while (!w2 && --j >= 0) w2 = bm2[j];
    if (!w2) return -1;
    const int Wp = (j << 5) | (31 - __clz(w2));
    return (Wp << 5) | (31 - __clz(bm1[Wp]));
}
__device__ __forceinline__ int next_ne(const unsigned* __restrict__ bm1,
                                       const unsigned* __restrict__ bm2, int b) {
    if (b >= BKT - 1) return -1;
    const int p = b + 1;
    unsigned w = bm1[p >> 5] & (~0u << (p & 31));
    if (w) return (p & ~31) | (__ffs(w) - 1);
    const int W = (p >> 5) + 1;
    if (W > 1023) return -1;
    int j = W >> 5;
    unsigned w2 = bm2[j] & (~0u << (W & 31));
    while (!w2 && ++j < 32) w2 = bm2[j];
    if (!w2) return -1;
    const int Wp = (j << 5) | (__ffs(w2) - 1);
    return (Wp << 5) | (__ffs(bm1[Wp]) - 1);
}

// Min |v - e| over one bucket's slot line: 4 independent uint4 loads,
// count-masked in registers (no divergent serial scalar loop). Slots beyond
// cnt are garbage but excluded by the j<c predicate.
__device__ __forceinline__ float scan_bucket(const unsigned* __restrict__ cnt,
                                             const float* __restrict__ slots,
                                             int side, int b, float v, float best) {
    const unsigned c = min(cnt[b], (unsigned)SLOTS);
    const float4* sl4 = (const float4*)(slots + ((size_t)(side * BKT + b)) * SLOTS);
    float e[SLOTS];
    *(float4*)(e + 0)  = sl4[0];
    *(float4*)(e + 4)  = sl4[1];
    *(float4*)(e + 8)  = sl4[2];
    *(float4*)(e + 12) = sl4[3];
#pragma unroll
    for (int j = 0; j < SLOTS; ++j) {
        const float d = fabsf(v - e[j]);
        best = ((unsigned)j < c) ? fminf(best, d) : best;
    }
    return best;
}

// ---- query: candidates = own bucket + nearest nonempty bucket below +
// nearest nonempty bucket above + overflow list. Exact: the value-order
// predecessor/successor of v are always in this candidate set (bucket map
// monotone; overflowed elements are in the scanned overflow list), every
// candidate is a real element, and f32 |v-y| rounding is monotone in true
// distance => min over candidates == min over all. Deterministic reduction.
__global__ __launch_bounds__(TPB) void
chamfer_query(const float* __restrict__ x, const float* __restrict__ y,
              int n, int m, const unsigned* __restrict__ ws,
              double* __restrict__ bsums) {
    const int q = blockIdx.x * TPB + threadIdx.x;
    const int total = n + m;
    double sx = 0.0, sy = 0.0;
    if (q < total) {
        const bool isx = q < n;
        const float v = isx ? x[q] : y[q - n];
        const int side = isx ? 1 : 0;            // search the OTHER side
        const unsigned* cnt = ws + CNT_OFF + side * BKT;
        const unsigned* bm1 = ws + BM1_OFF + side * 1024;
        const unsigned* bm2 = ws + BM2_OFF + side * 32;
        const float* slots = (const float*)(ws + SLOTS_OFF);
        const int b = bucket_of(v);

        float best = scan_bucket(cnt, slots, side, b, v, FLT_MAX);
        const int bp = prev_ne(bm1, bm2, b);
        if (bp >= 0) best = scan_bucket(cnt, slots, side, bp, v, best);
        const int bn = next_ne(bm1, bm2, b);
        if (bn >= 0) best = scan_bucket(cnt, slots, side, bn, v, best);

        const unsigned oc = min(ws[OVC_OFF + side], (unsigned)OVCAP);
        const float* ovf = (const float*)(ws + OVF_OFF) + side * OVCAP;
        for (unsigned k = 0; k < oc; ++k)
            best = fminf(best, fabsf(v - ovf[k]));

        if (isx) sx = (double)best; else sy = (double)best;
    }
    for (int off = 32; off > 0; off >>= 1) {
        sx += __shfl_down(sx, off);
        sy += __shfl_down(sy, off);
    }
    __shared__ double wsx[TPB / 64], wsy[TPB / 64];
    const int w = threadIdx.x >> 6;
    if ((threadIdx.x & 63) == 0) { wsx[w] = sx; wsy[w] = sy; }
    __syncthreads();
    if (threadIdx.x == 0) {
        double tx = 0.0, ty = 0.0;
#pragma unroll
        for (int i = 0; i < TPB / 64; ++i) { tx += wsx[i]; ty += wsy[i]; }
        bsums[2 * blockIdx.x] = tx;
        bsums[2 * blockIdx.x + 1] = ty;
    }
}

__global__ __launch_bounds__(TPB) void
chamfer_final(const double* __restrict__ bsums, int nb,
              int n, int m, float* __restrict__ out) {
    double sx = 0.0, sy = 0.0;
    for (int i = threadIdx.x; i < nb; i += blockDim.x) {
        sx += bsums[2 * i];
        sy += bsums[2 * i + 1];
    }
    for (int off = 32; off > 0; off >>= 1) {
        sx += __shfl_down(sx, off);
        sy += __shfl_down(sy, off);
    }
    __shared__ double lsx[4], lsy[4];
    const int wave = threadIdx.x >> 6;
    if ((threadIdx.x & 63) == 0) { lsx[wave] = sx; lsy[wave] = sy; }
    __syncthreads();
    if (threadIdx.x == 0) {
        double tx = 0.0, ty = 0.0;
        for (int w = 0; w < (int)(blockDim.x >> 6); ++w) { tx += lsx[w]; ty += lsy[w]; }
        const double a = (double)ALPHA;
        out[0] = (float)(a * tx / (double)n + (1.0 - a) * ty / (double)m);
    }
}

extern "C" void kernel_launch(void* const* d_in, const int* in_sizes, int n_in,
                              void* d_out, int out_size, void* d_ws, size_t ws_size,
                              hipStream_t stream) {
    const float* x = (const float*)d_in[0];
    const float* y = (const float*)d_in[1];
    const int n = in_sizes[0];
    const int m = in_sizes[1];
    float* out = (float*)d_out;
    const int total = n + m;

    unsigned* ws = (unsigned*)d_ws;
    const size_t meta_bytes = (size_t)(OVF_OFF + 2 * OVCAP) * sizeof(unsigned);
    const size_t meta_al = (meta_bytes + 255) & ~(size_t)255;
    double* bsums = (double*)((char*)d_ws + meta_al);

    const int nb = (total + TPB - 1) / TPB;   // 128 blocks

    hipMemsetAsync(ws, 0, (size_t)ZERO_WORDS * sizeof(unsigned), stream);
    chamfer_build<<<nb, TPB, 0, stream>>>(x, y, n, m, ws);
    chamfer_bitmap<<<1, BMT, 0, stream>>>(ws);
    chamfer_query<<<nb, TPB, 0, stream>>>(x, y, n, m, ws, bsums);
    chamfer_final<<<1, TPB, 0, stream>>>(bsums, nb, n, m, out);
}